// Round 1
// baseline (412.381 us; speedup 1.0000x reference)
//
#include <hip/hip_runtime.h>
#include <stdint.h>

typedef unsigned short u16;
typedef __attribute__((ext_vector_type(8))) __bf16 bf16x8;
typedef __attribute__((ext_vector_type(4))) float f32x4;
typedef __attribute__((ext_vector_type(8))) unsigned short ushort8;

__device__ __forceinline__ u16 f2bf(float f) {
  unsigned int u = __builtin_bit_cast(unsigned int, f);
  return (u16)((u + 0x7fffu + ((u >> 16) & 1u)) >> 16);
}

__device__ __forceinline__ f32x4 mfma16(bf16x8 a, bf16x8 b, f32x4 c) {
  return __builtin_amdgcn_mfma_f32_16x16x32_bf16(a, b, c, 0, 0, 0);
}

__device__ __forceinline__ void gload_lds16(const void* g, void* l) {
  __builtin_amdgcn_global_load_lds((const __attribute__((address_space(1))) void*)g,
                                   (__attribute__((address_space(3))) void*)l,
                                   16, 0, 0);
}

// ---------------- f32 -> bf16 convert ----------------
__global__ void __launch_bounds__(256) cvt_f32_bf16(const float* __restrict__ in,
                                                    u16* __restrict__ out, int n4) {
  int i = blockIdx.x * 256 + threadIdx.x;
  if (i >= n4) return;
  float4 v = ((const float4*)in)[i];
  u16 o0 = f2bf(v.x), o1 = f2bf(v.y), o2 = f2bf(v.z), o3 = f2bf(v.w);
  ushort8* dummy;
  (void)dummy;
  u16* dst = out + (size_t)i * 4;
  dst[0] = o0; dst[1] = o1; dst[2] = o2; dst[3] = o3;
}

// ---------------- NT GEMM: C[M,N] = A[M,K] @ B[N,K]^T + bias ----------------
// A, B bf16 row-major (K contiguous). 128x128 tile, BK=32, 4 waves (64x64 each).
template <int OUT_BF16>
__global__ void __launch_bounds__(256) gemm_nt(
    const u16* __restrict__ A, const u16* __restrict__ B,
    const float* __restrict__ bias, void* __restrict__ Cout,
    int M, int N, int K) {
  __shared__ alignas(16) u16 As[128 * 32];
  __shared__ alignas(16) u16 Bs[128 * 32];
  const int tid = threadIdx.x;
  const int wid = tid >> 6;
  const int lane = tid & 63;
  const long bm = (long)blockIdx.x * 128;
  const long bn = (long)blockIdx.y * 128;
  const int wr = (wid >> 1) * 64;
  const int wc = (wid & 1) * 64;

  f32x4 acc[4][4] = {};

  // staging: wave wid covers tile rows [wid*32, wid*32+32)
  const int srow = wid * 32 + (lane >> 2);   // + is*16
  const int skcol = (lane & 3) * 8;
  const u16* Abase = A + (bm + srow) * (long)K + skcol;
  const u16* Bbase = B + (bn + srow) * (long)K + skcol;
  u16* AsBase = As + wid * 1024;
  u16* BsBase = Bs + wid * 1024;

  const int fr = lane & 15;
  const int fk = (lane >> 4) * 8;

  for (int kt = 0; kt < K; kt += 32) {
    gload_lds16(Abase + kt, AsBase);
    gload_lds16(Abase + kt + (long)16 * K, AsBase + 512);
    gload_lds16(Bbase + kt, BsBase);
    gload_lds16(Bbase + kt + (long)16 * K, BsBase + 512);
    __syncthreads();
    bf16x8 af[4], bfr[4];
#pragma unroll
    for (int mi = 0; mi < 4; ++mi)
      af[mi] = *(const bf16x8*)(As + (wr + mi * 16 + fr) * 32 + fk);
#pragma unroll
    for (int ni = 0; ni < 4; ++ni)
      bfr[ni] = *(const bf16x8*)(Bs + (wc + ni * 16 + fr) * 32 + fk);
#pragma unroll
    for (int mi = 0; mi < 4; ++mi)
#pragma unroll
      for (int ni = 0; ni < 4; ++ni)
        acc[mi][ni] = mfma16(af[mi], bfr[ni], acc[mi][ni]);
    __syncthreads();
  }

  // epilogue: C layout col=lane&15, row=(lane>>4)*4+reg
  const int r0 = wr + ((lane >> 4) << 2);
  const int c0 = wc + (lane & 15);
#pragma unroll
  for (int mi = 0; mi < 4; ++mi) {
#pragma unroll
    for (int j = 0; j < 4; ++j) {
      long r = bm + r0 + mi * 16 + j;
#pragma unroll
      for (int ni = 0; ni < 4; ++ni) {
        long c = bn + c0 + ni * 16;
        float v = acc[mi][ni][j] + bias[c];
        if (OUT_BF16)
          ((u16*)Cout)[r * N + c] = f2bf(v);
        else
          ((float*)Cout)[r * N + c] = v;
      }
    }
  }
}

// ---------------- fused attention (self + prefix) ----------------
// grid: (S/64, H, B); 256 threads = 4 waves; wave handles 16 q-rows.
// qkv: [s*B+b][3*1024] bf16. attn_out: [s*B+b][1024] bf16.
__global__ void __launch_bounds__(256) attn_kernel(
    const u16* __restrict__ qkv, const float* __restrict__ prefix_pool,
    const int* __restrict__ prompt_ids, const float* __restrict__ batch_weight,
    u16* __restrict__ attn_out) {
  constexpr int E = 1024, E3 = 3072, BS = 32, L = 16;
  const int qc = blockIdx.x, h = blockIdx.y, b = blockIdx.z;
  const int tid = threadIdx.x;
  const int wid = tid >> 6, lane = tid & 63;

  __shared__ alignas(16) u16 Ks[64 * 64];   // [kv][d]
  __shared__ alignas(16) u16 VTs[64 * 64];  // [d][kv]
  __shared__ alignas(16) u16 Ps[4][16 * 64];

  const int fr = lane & 15;
  const int fkg = lane >> 4;  // 0..3
  u16* const pw = Ps[wid];
  const float scale = 0.125f;

  // Q fragments (2 K-chunks of 32)
  bf16x8 qf[2];
  {
    long m = (long)(qc * 64 + wid * 16 + fr) * BS + b;
    const u16* qp = qkv + m * E3 + h * 64 + fkg * 8;
    qf[0] = *(const bf16x8*)qp;
    qf[1] = *(const bf16x8*)(qp + 32);
  }

  float mrun[4], lrun[4];
#pragma unroll
  for (int j = 0; j < 4; ++j) { mrun[j] = -1e30f; lrun[j] = 0.f; }
  f32x4 oacc[4] = {};

  const int skv = wid * 16 + (lane >> 3);  // + is*8
  const int sd = (lane & 7) * 8;

  for (int kt = 0; kt < 8; ++kt) {
    // stage K tile [64][64] via global_load_lds (linear dest)
    {
      long m0 = (long)(kt * 64 + skv) * BS + b;
      const u16* src = qkv + m0 * E3 + E + h * 64 + sd;
      gload_lds16(src, Ks + wid * 1024);
      gload_lds16(src + (long)8 * BS * E3, Ks + wid * 1024 + 512);
    }
    // stage V transposed [d][kv] (reg-staged, per-thread)
    {
      int kv = tid >> 2;
      int d0 = (tid & 3) * 16;
      long m = (long)(kt * 64 + kv) * BS + b;
      const u16* src = qkv + m * E3 + 2 * E + h * 64 + d0;
      ushort8 t0 = *(const ushort8*)src;
      ushort8 t1 = *(const ushort8*)(src + 8);
#pragma unroll
      for (int i = 0; i < 8; ++i) VTs[(d0 + i) * 64 + kv] = t0[i];
#pragma unroll
      for (int i = 0; i < 8; ++i) VTs[(d0 + 8 + i) * 64 + kv] = t1[i];
    }
    __syncthreads();

    // S = Q K^T * scale   (16x64 per wave)
    f32x4 sa[4] = {};
#pragma unroll
    for (int kk = 0; kk < 2; ++kk) {
#pragma unroll
      for (int nt = 0; nt < 4; ++nt) {
        bf16x8 kf = *(const bf16x8*)(Ks + (nt * 16 + fr) * 64 + kk * 32 + fkg * 8);
        sa[nt] = mfma16(qf[kk], kf, sa[nt]);
      }
    }
#pragma unroll
    for (int nt = 0; nt < 4; ++nt) sa[nt] *= scale;

    // online softmax (row = fkg*4+j lives in the 16 lanes sharing fkg)
#pragma unroll
    for (int j = 0; j < 4; ++j) {
      float mx = fmaxf(fmaxf(sa[0][j], sa[1][j]), fmaxf(sa[2][j], sa[3][j]));
#pragma unroll
      for (int msk = 1; msk < 16; msk <<= 1) mx = fmaxf(mx, __shfl_xor(mx, msk, 64));
      mx = fmaxf(mx, mrun[j]);
      float alpha = __expf(mrun[j] - mx);
      mrun[j] = mx;
      float sum = 0.f;
#pragma unroll
      for (int nt = 0; nt < 4; ++nt) {
        float p = __expf(sa[nt][j] - mx);
        sa[nt][j] = p;
        sum += p;
      }
#pragma unroll
      for (int msk = 1; msk < 16; msk <<= 1) sum += __shfl_xor(sum, msk, 64);
      lrun[j] = lrun[j] * alpha + sum;
#pragma unroll
      for (int t = 0; t < 4; ++t) oacc[t][j] *= alpha;
    }
    // P -> LDS (wave-local), then O += P V
#pragma unroll
    for (int nt = 0; nt < 4; ++nt)
#pragma unroll
      for (int j = 0; j < 4; ++j)
        pw[(fkg * 4 + j) * 64 + nt * 16 + fr] = f2bf(sa[nt][j]);
#pragma unroll
    for (int kk = 0; kk < 2; ++kk) {
      bf16x8 pa = *(const bf16x8*)(pw + fr * 64 + kk * 32 + fkg * 8);
#pragma unroll
      for (int t = 0; t < 4; ++t) {
        bf16x8 vf = *(const bf16x8*)(VTs + (t * 16 + fr) * 64 + kk * 32 + fkg * 8);
        oacc[t] = mfma16(pa, vf, oacc[t]);
      }
    }
    __syncthreads();
  }

  // ---- prefix attention: L=16 keys, zero-padded to K=32 ----
  const int pid = prompt_ids[b];
  const float* pkb = prefix_pool + ((long)pid * 2 * L) * E + h * 64;
  const float* pvb = pkb + (long)L * E;
  {
    int lkv = tid >> 4;        // 0..15
    int d0 = (tid & 15) * 4;   // 0..60
    float4 v = *(const float4*)(pkb + (long)lkv * E + d0);
    u16* dst = Ks + lkv * 64 + d0;
    dst[0] = f2bf(v.x); dst[1] = f2bf(v.y); dst[2] = f2bf(v.z); dst[3] = f2bf(v.w);
  }
  {
    int d = tid >> 2;          // 0..63
    int kv0 = (tid & 3) * 8;   // 0,8,16,24
    u16 tmp[8];
#pragma unroll
    for (int i = 0; i < 8; ++i) {
      int kv = kv0 + i;
      float v = (kv < L) ? pvb[(long)kv * E + d] : 0.f;
      tmp[i] = f2bf(v);
    }
    *(ushort8*)(VTs + d * 32 + kv0) = *(const ushort8*)tmp;
  }
  __syncthreads();

  f32x4 sp = {};
#pragma unroll
  for (int kk = 0; kk < 2; ++kk) {
    bf16x8 kf = *(const bf16x8*)(Ks + fr * 64 + kk * 32 + fkg * 8);
    sp = mfma16(qf[kk], kf, sp);
  }
  sp *= scale;
  float lp[4];
#pragma unroll
  for (int j = 0; j < 4; ++j) {
    float mx = sp[j];
#pragma unroll
    for (int msk = 1; msk < 16; msk <<= 1) mx = fmaxf(mx, __shfl_xor(mx, msk, 64));
    float p = __expf(sp[j] - mx);
    sp[j] = p;
    float sum = p;
#pragma unroll
    for (int msk = 1; msk < 16; msk <<= 1) sum += __shfl_xor(sum, msk, 64);
    lp[j] = sum;
  }
#pragma unroll
  for (int j = 0; j < 4; ++j) {
    int row = fkg * 4 + j;
    pw[row * 32 + fr] = f2bf(sp[j]);
    pw[row * 32 + 16 + fr] = 0;
  }
  f32x4 opacc[4] = {};
  {
    bf16x8 pa = *(const bf16x8*)(pw + fr * 32 + fkg * 8);
#pragma unroll
    for (int t = 0; t < 4; ++t) {
      bf16x8 vf = *(const bf16x8*)(VTs + (t * 16 + fr) * 32 + fkg * 8);
      opacc[t] = mfma16(pa, vf, opacc[t]);
    }
  }

  const float bw = batch_weight[b];
#pragma unroll
  for (int j = 0; j < 4; ++j) {
    long m = (long)(qc * 64 + wid * 16 + fkg * 4 + j) * BS + b;
    float invl = 1.f / lrun[j];
    float invlp = 1.f / lp[j];
#pragma unroll
    for (int t = 0; t < 4; ++t) {
      float v = oacc[t][j] * invl + bw * opacc[t][j] * invlp;
      attn_out[m * E + h * 64 + t * 16 + fr] = f2bf(v);
    }
  }
}

extern "C" void kernel_launch(void* const* d_in, const int* in_sizes, int n_in,
                              void* d_out, int out_size, void* d_ws, size_t ws_size,
                              hipStream_t stream) {
  const float* query = (const float*)d_in[0];
  const int* prompt_ids = (const int*)d_in[1];
  const float* batch_weight = (const float*)d_in[2];
  const float* in_proj_w = (const float*)d_in[3];
  const float* in_proj_b = (const float*)d_in[4];
  const float* out_proj_w = (const float*)d_in[5];
  const float* out_proj_b = (const float*)d_in[6];
  const float* prefix_pool = (const float*)d_in[7];
  float* out = (float*)d_out;

  // workspace layout (bf16 intermediates), ~168 MB
  u16* qbf = (u16*)d_ws;                        // 16384x1024
  u16* wqkv = qbf + (size_t)16384 * 1024;       // 3072x1024
  u16* wout = wqkv + (size_t)3072 * 1024;       // 1024x1024
  u16* qkvb = wout + (size_t)1024 * 1024;       // 16384x3072
  u16* attnb = qkvb + (size_t)16384 * 3072;     // 16384x1024

  cvt_f32_bf16<<<16384, 256, 0, stream>>>(query, qbf, 16384 * 1024 / 4);
  cvt_f32_bf16<<<3072, 256, 0, stream>>>(in_proj_w, wqkv, 3072 * 1024 / 4);
  cvt_f32_bf16<<<1024, 256, 0, stream>>>(out_proj_w, wout, 1024 * 1024 / 4);

  gemm_nt<1><<<dim3(128, 24), 256, 0, stream>>>(qbf, wqkv, in_proj_b, qkvb,
                                                16384, 3072, 1024);
  attn_kernel<<<dim3(8, 16, 32), 256, 0, stream>>>(qkvb, prefix_pool, prompt_ids,
                                                   batch_weight, attnb);
  gemm_nt<0><<<dim3(128, 8), 256, 0, stream>>>(attnb, wout, out_proj_b, out,
                                               16384, 1024, 1024);
}

// Round 2
// 391.968 us; speedup vs baseline: 1.0521x; 1.0521x over previous
//
#include <hip/hip_runtime.h>
#include <stdint.h>

typedef unsigned short u16;
typedef __attribute__((ext_vector_type(8))) __bf16 bf16x8;
typedef __attribute__((ext_vector_type(4))) float f32x4;
typedef __attribute__((ext_vector_type(8))) unsigned short ushort8;

__device__ __forceinline__ u16 f2bf(float f) {
  unsigned int u = __builtin_bit_cast(unsigned int, f);
  return (u16)((u + 0x7fffu + ((u >> 16) & 1u)) >> 16);
}

__device__ __forceinline__ f32x4 mfma16(bf16x8 a, bf16x8 b, f32x4 c) {
  return __builtin_amdgcn_mfma_f32_16x16x32_bf16(a, b, c, 0, 0, 0);
}

__device__ __forceinline__ void gload_lds16(const void* g, void* l) {
  __builtin_amdgcn_global_load_lds((const __attribute__((address_space(1))) void*)g,
                                   (__attribute__((address_space(3))) void*)l,
                                   16, 0, 0);
}

// ---------------- f32 -> bf16 convert ----------------
__global__ void __launch_bounds__(256) cvt_f32_bf16(const float* __restrict__ in,
                                                    u16* __restrict__ out, int n4) {
  int i = blockIdx.x * 256 + threadIdx.x;
  if (i >= n4) return;
  float4 v = ((const float4*)in)[i];
  u16* dst = out + (size_t)i * 4;
  dst[0] = f2bf(v.x); dst[1] = f2bf(v.y); dst[2] = f2bf(v.z); dst[3] = f2bf(v.w);
}

// ---------------- NT GEMM: C[M,N] = A[M,K] @ B[N,K]^T + bias ----------------
// MODE 0: f32 row-major out. MODE 1: bf16 row-major out.
// MODE 2: scatter qkv into q/k/v [b,h,s,d] bf16 (M index = s*32+b, N=3072).
template <int MODE>
__global__ void __launch_bounds__(256) gemm_nt(
    const u16* __restrict__ A, const u16* __restrict__ B,
    const float* __restrict__ bias, void* __restrict__ Cout,
    u16* __restrict__ q_out, u16* __restrict__ k_out, u16* __restrict__ v_out,
    int M, int N, int K) {
  __shared__ alignas(16) u16 As[128 * 32];
  __shared__ alignas(16) u16 Bs[128 * 32];
  const int tid = threadIdx.x;
  const int wid = tid >> 6;
  const int lane = tid & 63;
  const long bm = (long)blockIdx.x * 128;
  const long bn = (long)blockIdx.y * 128;
  const int wr = (wid >> 1) * 64;
  const int wc = (wid & 1) * 64;

  f32x4 acc[4][4] = {};

  const int srow = wid * 32 + (lane >> 2);
  const int skcol = (lane & 3) * 8;
  const u16* Abase = A + (bm + srow) * (long)K + skcol;
  const u16* Bbase = B + (bn + srow) * (long)K + skcol;
  u16* AsBase = As + wid * 1024;
  u16* BsBase = Bs + wid * 1024;

  const int fr = lane & 15;
  const int fk = (lane >> 4) * 8;

  for (int kt = 0; kt < K; kt += 32) {
    gload_lds16(Abase + kt, AsBase);
    gload_lds16(Abase + kt + (long)16 * K, AsBase + 512);
    gload_lds16(Bbase + kt, BsBase);
    gload_lds16(Bbase + kt + (long)16 * K, BsBase + 512);
    __syncthreads();
    bf16x8 af[4], bfr[4];
#pragma unroll
    for (int mi = 0; mi < 4; ++mi)
      af[mi] = *(const bf16x8*)(As + (wr + mi * 16 + fr) * 32 + fk);
#pragma unroll
    for (int ni = 0; ni < 4; ++ni)
      bfr[ni] = *(const bf16x8*)(Bs + (wc + ni * 16 + fr) * 32 + fk);
#pragma unroll
    for (int mi = 0; mi < 4; ++mi)
#pragma unroll
      for (int ni = 0; ni < 4; ++ni)
        acc[mi][ni] = mfma16(af[mi], bfr[ni], acc[mi][ni]);
    __syncthreads();
  }

  const int r0 = wr + ((lane >> 4) << 2);
  const int c0 = wc + (lane & 15);
#pragma unroll
  for (int mi = 0; mi < 4; ++mi) {
#pragma unroll
    for (int j = 0; j < 4; ++j) {
      long r = bm + r0 + mi * 16 + j;
#pragma unroll
      for (int ni = 0; ni < 4; ++ni) {
        long c = bn + c0 + ni * 16;
        float v = acc[mi][ni][j] + bias[c];
        if (MODE == 0) {
          ((float*)Cout)[r * N + c] = v;
        } else if (MODE == 1) {
          ((u16*)Cout)[r * N + c] = f2bf(v);
        } else {
          // r = s*32 + b ; c -> (sec, h, d)
          int s = (int)(r >> 5), bb = (int)(r & 31);
          int sec = (int)(c >> 10), e = (int)(c & 1023);
          int hh = e >> 6, d = e & 63;
          u16* dst = (sec == 0) ? q_out : (sec == 1) ? k_out : v_out;
          dst[(((size_t)(bb * 16 + hh) * 512 + s) * 64) + d] = f2bf(v);
        }
      }
    }
  }
}

// ---------------- fused attention v2 (self + prefix) ----------------
// grid (h=16, b=32); 512 threads = 8 waves; wave w owns q rows [w*64, w*64+64).
// K/V fully LDS-resident per (b,h), XOR-swizzled against bank conflicts.
__global__ void __launch_bounds__(512) attn_v2(
    const u16* __restrict__ Q, const u16* __restrict__ K, const u16* __restrict__ V,
    const float* __restrict__ prefix_pool, const int* __restrict__ prompt_ids,
    const float* __restrict__ batch_weight, u16* __restrict__ attn_out) {
  constexpr int S = 512, D = 64, E = 1024, L = 16;
  const int h = blockIdx.x, b = blockIdx.y;
  const int tid = threadIdx.x;
  const int wid = tid >> 6, lane = tid & 63;
  const int fr = lane & 15, fkg = lane >> 4;
  const float scale = 0.125f;

  __shared__ alignas(16) u16 Ks[S * D];     // [s][d], elem ^= (s&7)<<3
  __shared__ alignas(16) u16 VTs[D * S];    // [d][s], elem ^= (d&7)<<3
  __shared__ alignas(16) u16 pKs[L * D];    // [l][d], elem ^= (l&7)<<3
  __shared__ alignas(16) u16 pVTs[D * 32];  // [d][kv], unswizzled (already conflict-free)
  __shared__ alignas(16) u16 Ps[8][16 * 64];// per-wave P, elem ^= (r&7)<<3

  const size_t bh = (size_t)(b * 16 + h);
  const u16* Kbase = K + bh * S * D;
  const u16* Vbase = V + bh * S * D;
  const u16* Qbase = Q + bh * S * D;

  // ---- stage K (swizzled, reg-staged b128) ----
#pragma unroll
  for (int i = 0; i < 8; ++i) {
    int row = i * 64 + (tid >> 3);
    int c8 = (tid & 7) * 8;
    ushort8 val = *(const ushort8*)(Kbase + row * 64 + c8);
    int e = (row * 64 + c8) ^ ((row & 7) << 3);
    *(ushort8*)(Ks + e) = val;
  }
  // ---- build V^T (swizzled; scalar writes, conflict-free: lanes span s) ----
  {
    int s = tid;
    const ushort8* vp = (const ushort8*)(Vbase + s * 64);
#pragma unroll
    for (int c8 = 0; c8 < 8; ++c8) {
      ushort8 v8 = vp[c8];
#pragma unroll
      for (int i = 0; i < 8; ++i) {
        int d = c8 * 8 + i;
        VTs[(d * 512 + s) ^ ((d & 7) << 3)] = v8[i];
      }
    }
  }
  // ---- stage prefix K/V (f32 -> bf16) ----
  const int pid = prompt_ids[b];
  const float* pk = prefix_pool + ((size_t)pid * 2 * L) * E + h * 64;
  const float* pv = pk + (size_t)L * E;
  if (tid < 256) {
    int l = tid >> 4, d0 = (tid & 15) * 4;
    float4 v = *(const float4*)(pk + (size_t)l * E + d0);
    u16 t4[4] = {f2bf(v.x), f2bf(v.y), f2bf(v.z), f2bf(v.w)};
#pragma unroll
    for (int i = 0; i < 4; ++i)
      pKs[(l * 64 + d0 + i) ^ ((l & 7) << 3)] = t4[i];
  } else {
    int t = tid - 256;
    int d = t >> 2, kv0 = (t & 3) * 8;
#pragma unroll
    for (int i = 0; i < 8; ++i) {
      int kv = kv0 + i;
      float v = (kv < L) ? pv[(size_t)kv * E + d] : 0.f;
      pVTs[d * 32 + kv] = f2bf(v);
    }
  }
  __syncthreads();

  u16* const pw = Ps[wid];
  const float bwv = batch_weight[b];

  for (int mt = 0; mt < 4; ++mt) {
    const int qrow = wid * 64 + mt * 16 + fr;
    bf16x8 qf0 = *(const bf16x8*)(Qbase + qrow * 64 + fkg * 8);
    bf16x8 qf1 = *(const bf16x8*)(Qbase + qrow * 64 + 32 + fkg * 8);

    float mrun[4], lrun[4];
#pragma unroll
    for (int j = 0; j < 4; ++j) { mrun[j] = -1e30f; lrun[j] = 0.f; }
    f32x4 oacc[4] = {};

    for (int c = 0; c < 8; ++c) {
      // S = Q K^T
      f32x4 sa[4] = {};
#pragma unroll
      for (int nt = 0; nt < 4; ++nt) {
        int krow = c * 64 + nt * 16 + fr;
        int base = krow * 64;
        bf16x8 kf0 = *(const bf16x8*)(Ks + ((base + fkg * 8) ^ ((krow & 7) << 3)));
        bf16x8 kf1 = *(const bf16x8*)(Ks + ((base + 32 + fkg * 8) ^ ((krow & 7) << 3)));
        sa[nt] = mfma16(qf0, kf0, sa[nt]);
        sa[nt] = mfma16(qf1, kf1, sa[nt]);
      }
#pragma unroll
      for (int nt = 0; nt < 4; ++nt) sa[nt] *= scale;

      // online softmax with defer-max (THR=8)
#pragma unroll
      for (int j = 0; j < 4; ++j) {
        float mx = fmaxf(fmaxf(sa[0][j], sa[1][j]), fmaxf(sa[2][j], sa[3][j]));
#pragma unroll
        for (int msk = 1; msk < 16; msk <<= 1) mx = fmaxf(mx, __shfl_xor(mx, msk, 64));
        float mnew;
        if (__all(mx <= mrun[j] + 8.0f)) {
          mnew = mrun[j];
        } else {
          mnew = fmaxf(mx, mrun[j]);
          float alpha = __expf(mrun[j] - mnew);
          lrun[j] *= alpha;
#pragma unroll
          for (int t = 0; t < 4; ++t) oacc[t][j] *= alpha;
          mrun[j] = mnew;
        }
        float sum = 0.f;
#pragma unroll
        for (int nt = 0; nt < 4; ++nt) {
          float p = __expf(sa[nt][j] - mnew);
          sa[nt][j] = p;
          sum += p;
        }
#pragma unroll
        for (int msk = 1; msk < 16; msk <<= 1) sum += __shfl_xor(sum, msk, 64);
        lrun[j] += sum;
      }

      // P -> LDS (wave-local, swizzled)
#pragma unroll
      for (int nt = 0; nt < 4; ++nt)
#pragma unroll
        for (int j = 0; j < 4; ++j) {
          int r = fkg * 4 + j;
          pw[(r * 64 + nt * 16 + fr) ^ ((r & 7) << 3)] = f2bf(sa[nt][j]);
        }
      // O += P V
#pragma unroll
      for (int kk = 0; kk < 2; ++kk) {
        bf16x8 pa = *(const bf16x8*)(pw + ((fr * 64 + kk * 32 + fkg * 8) ^ ((fr & 7) << 3)));
#pragma unroll
        for (int t = 0; t < 4; ++t) {
          int vd = t * 16 + fr;
          bf16x8 vf = *(const bf16x8*)(VTs + ((vd * 512 + c * 64 + kk * 32 + fkg * 8) ^ ((vd & 7) << 3)));
          oacc[t] = mfma16(pa, vf, oacc[t]);
        }
      }
    }

    // ---- prefix attention (L=16, padded to K=32) ----
    f32x4 sp = {};
    {
      bf16x8 pk0 = *(const bf16x8*)(pKs + ((fr * 64 + fkg * 8) ^ ((fr & 7) << 3)));
      bf16x8 pk1 = *(const bf16x8*)(pKs + ((fr * 64 + 32 + fkg * 8) ^ ((fr & 7) << 3)));
      sp = mfma16(qf0, pk0, sp);
      sp = mfma16(qf1, pk1, sp);
    }
    sp *= scale;
    float lp[4];
#pragma unroll
    for (int j = 0; j < 4; ++j) {
      float mx = sp[j];
#pragma unroll
      for (int msk = 1; msk < 16; msk <<= 1) mx = fmaxf(mx, __shfl_xor(mx, msk, 64));
      float p = __expf(sp[j] - mx);
      sp[j] = p;
      float sum = p;
#pragma unroll
      for (int msk = 1; msk < 16; msk <<= 1) sum += __shfl_xor(sum, msk, 64);
      lp[j] = sum;
    }
#pragma unroll
    for (int j = 0; j < 4; ++j) {
      int r = fkg * 4 + j;
      pw[(r * 64 + fr) ^ ((r & 7) << 3)] = f2bf(sp[j]);
      pw[(r * 64 + 16 + fr) ^ ((r & 7) << 3)] = 0;
    }
    f32x4 opacc[4] = {};
    {
      bf16x8 pa = *(const bf16x8*)(pw + ((fr * 64 + fkg * 8) ^ ((fr & 7) << 3)));
#pragma unroll
      for (int t = 0; t < 4; ++t) {
        bf16x8 vf = *(const bf16x8*)(pVTs + (t * 16 + fr) * 32 + fkg * 8);
        opacc[t] = mfma16(pa, vf, opacc[t]);
      }
    }

    // ---- epilogue: combine + write ----
#pragma unroll
    for (int j = 0; j < 4; ++j) {
      int s = wid * 64 + mt * 16 + fkg * 4 + j;
      float invl = 1.f / lrun[j];
      float invlp = 1.f / lp[j];
      size_t m = (size_t)s * 32 + b;
#pragma unroll
      for (int t = 0; t < 4; ++t) {
        float v = oacc[t][j] * invl + bwv * opacc[t][j] * invlp;
        attn_out[m * E + h * 64 + t * 16 + fr] = f2bf(v);
      }
    }
  }
}

extern "C" void kernel_launch(void* const* d_in, const int* in_sizes, int n_in,
                              void* d_out, int out_size, void* d_ws, size_t ws_size,
                              hipStream_t stream) {
  const float* query = (const float*)d_in[0];
  const int* prompt_ids = (const int*)d_in[1];
  const float* batch_weight = (const float*)d_in[2];
  const float* in_proj_w = (const float*)d_in[3];
  const float* in_proj_b = (const float*)d_in[4];
  const float* out_proj_w = (const float*)d_in[5];
  const float* out_proj_b = (const float*)d_in[6];
  const float* prefix_pool = (const float*)d_in[7];
  float* out = (float*)d_out;

  // workspace layout (bf16), ~176 MB
  u16* qbf = (u16*)d_ws;                      // 16384x1024 (GEMM1 A)
  u16* wqkv = qbf + (size_t)16384 * 1024;     // 3072x1024
  u16* wout = wqkv + (size_t)3072 * 1024;     // 1024x1024
  u16* qx = wout + (size_t)1024 * 1024;       // [b,h,s,d] 32*16*512*64
  u16* kx = qx + (size_t)32 * 16 * 512 * 64;
  u16* vx = kx + (size_t)32 * 16 * 512 * 64;
  u16* attnb = vx + (size_t)32 * 16 * 512 * 64;  // 16384x1024

  cvt_f32_bf16<<<16384, 256, 0, stream>>>(query, qbf, 16384 * 1024 / 4);
  cvt_f32_bf16<<<3072, 256, 0, stream>>>(in_proj_w, wqkv, 3072 * 1024 / 4);
  cvt_f32_bf16<<<1024, 256, 0, stream>>>(out_proj_w, wout, 1024 * 1024 / 4);

  gemm_nt<2><<<dim3(128, 24), 256, 0, stream>>>(qbf, wqkv, in_proj_b, nullptr,
                                                qx, kx, vx, 16384, 3072, 1024);
  attn_v2<<<dim3(16, 32), 512, 0, stream>>>(qx, kx, vx, prefix_pool, prompt_ids,
                                            batch_weight, attnb);
  gemm_nt<0><<<dim3(128, 8), 256, 0, stream>>>(attnb, wout, out_proj_b, out,
                                               nullptr, nullptr, nullptr,
                                               16384, 1024, 1024);
}

// Round 3
// 324.191 us; speedup vs baseline: 1.2720x; 1.2091x over previous
//
#include <hip/hip_runtime.h>
#include <stdint.h>

typedef unsigned short u16;
typedef __attribute__((ext_vector_type(8))) __bf16 bf16x8;
typedef __attribute__((ext_vector_type(4))) float f32x4;
typedef __attribute__((ext_vector_type(8))) unsigned short ushort8;

__device__ __forceinline__ u16 f2bf(float f) {
  unsigned int u = __builtin_bit_cast(unsigned int, f);
  return (u16)((u + 0x7fffu + ((u >> 16) & 1u)) >> 16);
}

__device__ __forceinline__ f32x4 mfma16(bf16x8 a, bf16x8 b, f32x4 c) {
  return __builtin_amdgcn_mfma_f32_16x16x32_bf16(a, b, c, 0, 0, 0);
}

__device__ __forceinline__ void gload_lds16(const void* g, void* l) {
  __builtin_amdgcn_global_load_lds((const __attribute__((address_space(1))) void*)g,
                                   (__attribute__((address_space(3))) void*)l,
                                   16, 0, 0);
}

// ---------------- f32 -> bf16 convert ----------------
__global__ void __launch_bounds__(256) cvt_f32_bf16(const float* __restrict__ in,
                                                    u16* __restrict__ out, int n4) {
  int i = blockIdx.x * 256 + threadIdx.x;
  if (i >= n4) return;
  float4 v = ((const float4*)in)[i];
  u16* dst = out + (size_t)i * 4;
  dst[0] = f2bf(v.x); dst[1] = f2bf(v.y); dst[2] = f2bf(v.z); dst[3] = f2bf(v.w);
}

// ================= 256x256 8-phase NT GEMM =================
// C[M,N] = A[M,K] @ B[N,K]^T + bias. BK=64, 8 waves (2Mx4N), 512 thr.
// LDS: 2 K-tile buffers per matrix, [256][64] bf16, chunk-XOR swizzle
// (chunk ^= row&7). Stage = linear LDS dest + pre-swizzled global src.
// MODE 0: f32 row-major out. MODE 2: scatter qkv -> q/k/v [b,h,s,d] bf16.

#define LDV(p) (*(const bf16x8*)(p))
#define RD_LO(AS, C) { aL[0]=LDV(AS+aRow+(C)); aL[1]=LDV(AS+aRow+1024+(C)); \
                       aL[2]=LDV(AS+aRow+2048+(C)); aL[3]=LDV(AS+aRow+3072+(C)); }
#define RD_HI(AS, C) { aH[0]=LDV(AS+aRow+4096+(C)); aH[1]=LDV(AS+aRow+5120+(C)); \
                       aH[2]=LDV(AS+aRow+6144+(C)); aH[3]=LDV(AS+aRow+7168+(C)); }
#define RD_B(BS, R, C) { R[0]=LDV(BS+bRow+(C)); R[1]=LDV(BS+bRow+1024+(C)); \
                         R[2]=LDV(BS+bRow+2048+(C)); R[3]=LDV(BS+bRow+3072+(C)); }
#define STA(DST, Q, T) gload_lds16(baseA + (Q)*K64 + (size_t)(T)*64, (DST) + (Q)*4096 + stDst)
#define STB(DST, Q, T) gload_lds16(baseB + (Q)*K64 + (size_t)(T)*64, (DST) + (Q)*4096 + stDst)
#define MM_LO(BB) { _Pragma("unroll") for (int mi=0;mi<4;++mi) \
                    _Pragma("unroll") for (int ni=0;ni<4;++ni) \
                      acc[mi][ni]=mfma16(aL[mi],(BB)[ni],acc[mi][ni]); }
#define MM_HI(BB) { _Pragma("unroll") for (int mi=0;mi<4;++mi) \
                    _Pragma("unroll") for (int ni=0;ni<4;++ni) \
                      acc[mi+4][ni]=mfma16(aH[mi],(BB)[ni],acc[mi+4][ni]); }
#define VMW(N) asm volatile("s_waitcnt vmcnt(" #N ")" ::: "memory")
#define BAR() __builtin_amdgcn_s_barrier()
#define LK0() { asm volatile("s_waitcnt lgkmcnt(0)" ::: "memory"); \
                __builtin_amdgcn_sched_barrier(0); }
#define PRIO1() __builtin_amdgcn_s_setprio(1)
#define PRIO0() __builtin_amdgcn_s_setprio(0)
#define MFMA_PH(MM, BB) { PRIO1(); MM(BB); PRIO0(); }

template <int MODE>
__global__ void __launch_bounds__(512, 2) gemm8p(
    const u16* __restrict__ A, const u16* __restrict__ B,
    const float* __restrict__ bias, void* __restrict__ Cout,
    u16* __restrict__ q_out, u16* __restrict__ k_out, u16* __restrict__ v_out,
    int M, int N, int K) {
  __shared__ alignas(16) u16 As[2][16384];
  __shared__ alignas(16) u16 Bs[2][16384];

  const int tid = threadIdx.x;
  const int w = tid >> 6, l = tid & 63;
  const int wm = w >> 2, wn = w & 3;
  const int fr = l & 15, fkg = l >> 4;
  const long bm = (long)blockIdx.x * 256;
  const long bn = (long)blockIdx.y * 256;
  const int NT = K >> 6;        // K-tiles of 64
  const int NIT = NT >> 1;      // iterations (2 tiles each)

  // stage source bases (per-lane, pre-swizzled chunk)
  const int srow = w * 8 + (l >> 3);
  const int schk = ((l & 7) ^ (l >> 3)) * 8;
  const u16* baseA = A + (bm + srow) * (size_t)K + schk;
  const u16* baseB = B + (bn + srow) * (size_t)K + schk;
  const size_t K64 = (size_t)K * 64;
  const int stDst = w * 512;

  u16* const as0 = &As[0][0]; u16* const as1 = &As[1][0];
  u16* const bs0 = &Bs[0][0]; u16* const bs1 = &Bs[1][0];

  // fragment read offsets (swizzled)
  const int sw = (fr & 7) << 3;
  const int c0 = (fkg * 8) ^ sw;
  const int c1 = (32 + fkg * 8) ^ sw;
  const int aRow = (wm * 128 + fr) * 64;
  const int bRow = (wn * 64 + fr) * 64;

  f32x4 acc[8][4] = {};
  bf16x8 aL[4], aH[4], b0[4], b1[4];

  // ---- prologue: B(t0)q0..3, A(t0)q0,2,1,3, B(t1)q0,1  (10 loads) ----
  STB(bs0, 0, 0); STB(bs0, 1, 0);
  STB(bs0, 2, 0); STB(bs0, 3, 0);
  STA(as0, 0, 0); STA(as0, 2, 0);
  STA(as0, 1, 0); STA(as0, 3, 0);
  STB(bs1, 0, 1); STB(bs1, 1, 1);
  VMW(4); BAR();

  for (int it = 0; it < NIT - 1; ++it) {
    const int t1 = 2 * it + 1, t2 = 2 * it + 2, t3 = 2 * it + 3;
    // P1
    RD_LO(as0, c0); RD_B(bs0, b0, c0);
    STB(bs1, 2, t1); STB(bs1, 3, t1);
    VMW(4); BAR(); LK0(); MFMA_PH(MM_LO, b0); BAR();
    // P2
    RD_HI(as0, c0);
    STA(as1, 0, t1); STA(as1, 2, t1);
    BAR(); LK0(); MFMA_PH(MM_HI, b0); BAR();
    // P3
    RD_LO(as0, c1); RD_B(bs0, b1, c1);
    STA(as1, 1, t1); STA(as1, 3, t1);
    BAR(); LK0(); MFMA_PH(MM_LO, b1); BAR();
    // P4
    RD_HI(as0, c1);
    STB(bs0, 0, t2); STB(bs0, 1, t2);
    VMW(4); BAR(); LK0(); MFMA_PH(MM_HI, b1); BAR();
    // P5
    RD_LO(as1, c0); RD_B(bs1, b0, c0);
    STB(bs0, 2, t2); STB(bs0, 3, t2);
    VMW(4); BAR(); LK0(); MFMA_PH(MM_LO, b0); BAR();
    // P6
    RD_HI(as1, c0);
    STA(as0, 0, t2); STA(as0, 2, t2);
    BAR(); LK0(); MFMA_PH(MM_HI, b0); BAR();
    // P7
    RD_LO(as1, c1); RD_B(bs1, b1, c1);
    STA(as0, 1, t2); STA(as0, 3, t2);
    BAR(); LK0(); MFMA_PH(MM_LO, b1); BAR();
    // P8
    RD_HI(as1, c1);
    STB(bs1, 0, t3); STB(bs1, 1, t3);
    VMW(4); BAR(); LK0(); MFMA_PH(MM_HI, b1); BAR();
  }

  // ---- peeled last iteration (t1 = NT-1; no t2/t3 stages) ----
  {
    const int t1 = NT - 1;
    // P1
    RD_LO(as0, c0); RD_B(bs0, b0, c0);
    STB(bs1, 2, t1); STB(bs1, 3, t1);
    VMW(4); BAR(); LK0(); MFMA_PH(MM_LO, b0); BAR();
    // P2
    RD_HI(as0, c0);
    STA(as1, 0, t1); STA(as1, 2, t1);
    BAR(); LK0(); MFMA_PH(MM_HI, b0); BAR();
    // P3
    RD_LO(as0, c1); RD_B(bs0, b1, c1);
    STA(as1, 1, t1); STA(as1, 3, t1);
    BAR(); LK0(); MFMA_PH(MM_LO, b1); BAR();
    // P4
    RD_HI(as0, c1);
    VMW(2); BAR(); LK0(); MFMA_PH(MM_HI, b1); BAR();
    // P5
    RD_LO(as1, c0); RD_B(bs1, b0, c0);
    VMW(0); BAR(); LK0(); MFMA_PH(MM_LO, b0); BAR();
    // P6
    RD_HI(as1, c0);
    BAR(); LK0(); MFMA_PH(MM_HI, b0); BAR();
    // P7
    RD_LO(as1, c1); RD_B(bs1, b1, c1);
    BAR(); LK0(); MFMA_PH(MM_LO, b1); BAR();
    // P8
    RD_HI(as1, c1);
    BAR(); LK0(); MFMA_PH(MM_HI, b1);
  }

  // ---- epilogue ----
  const int r0 = wm * 128 + ((l >> 4) << 2);
  const int cc0 = wn * 64 + (l & 15);
#pragma unroll
  for (int mi = 0; mi < 8; ++mi) {
#pragma unroll
    for (int j = 0; j < 4; ++j) {
      long r = bm + r0 + mi * 16 + j;
#pragma unroll
      for (int ni = 0; ni < 4; ++ni) {
        long c = bn + cc0 + ni * 16;
        float v = acc[mi][ni][j] + bias[c];
        if (MODE == 0) {
          ((float*)Cout)[r * N + c] = v;
        } else {
          int s = (int)(r >> 5), bb = (int)(r & 31);
          int sec = (int)(c >> 10), e = (int)(c & 1023);
          int hh = e >> 6, d = e & 63;
          u16* dst = (sec == 0) ? q_out : (sec == 1) ? k_out : v_out;
          dst[(((size_t)(bb * 16 + hh) * 512 + s) * 64) + d] = f2bf(v);
        }
      }
    }
  }
}

// ---------------- fused attention v2 (self + prefix) ----------------
__global__ void __launch_bounds__(512) attn_v2(
    const u16* __restrict__ Q, const u16* __restrict__ K, const u16* __restrict__ V,
    const float* __restrict__ prefix_pool, const int* __restrict__ prompt_ids,
    const float* __restrict__ batch_weight, u16* __restrict__ attn_out) {
  constexpr int S = 512, D = 64, E = 1024, L = 16;
  const int h = blockIdx.x, b = blockIdx.y;
  const int tid = threadIdx.x;
  const int wid = tid >> 6, lane = tid & 63;
  const int fr = lane & 15, fkg = lane >> 4;
  const float scale = 0.125f;

  __shared__ alignas(16) u16 Ks[S * D];
  __shared__ alignas(16) u16 VTs[D * S];
  __shared__ alignas(16) u16 pKs[L * D];
  __shared__ alignas(16) u16 pVTs[D * 32];
  __shared__ alignas(16) u16 Ps[8][16 * 64];

  const size_t bh = (size_t)(b * 16 + h);
  const u16* Kbase = K + bh * S * D;
  const u16* Vbase = V + bh * S * D;
  const u16* Qbase = Q + bh * S * D;

#pragma unroll
  for (int i = 0; i < 8; ++i) {
    int row = i * 64 + (tid >> 3);
    int c8 = (tid & 7) * 8;
    ushort8 val = *(const ushort8*)(Kbase + row * 64 + c8);
    int e = (row * 64 + c8) ^ ((row & 7) << 3);
    *(ushort8*)(Ks + e) = val;
  }
  {
    int s = tid;
    const ushort8* vp = (const ushort8*)(Vbase + s * 64);
#pragma unroll
    for (int c8 = 0; c8 < 8; ++c8) {
      ushort8 v8 = vp[c8];
#pragma unroll
      for (int i = 0; i < 8; ++i) {
        int d = c8 * 8 + i;
        VTs[(d * 512 + s) ^ ((d & 7) << 3)] = v8[i];
      }
    }
  }
  const int pid = prompt_ids[b];
  const float* pk = prefix_pool + ((size_t)pid * 2 * L) * E + h * 64;
  const float* pv = pk + (size_t)L * E;
  if (tid < 256) {
    int ll = tid >> 4, d0 = (tid & 15) * 4;
    float4 v = *(const float4*)(pk + (size_t)ll * E + d0);
    u16 t4[4] = {f2bf(v.x), f2bf(v.y), f2bf(v.z), f2bf(v.w)};
#pragma unroll
    for (int i = 0; i < 4; ++i)
      pKs[(ll * 64 + d0 + i) ^ ((ll & 7) << 3)] = t4[i];
  } else {
    int t = tid - 256;
    int d = t >> 2, kv0 = (t & 3) * 8;
#pragma unroll
    for (int i = 0; i < 8; ++i) {
      int kv = kv0 + i;
      float v = (kv < L) ? pv[(size_t)kv * E + d] : 0.f;
      pVTs[d * 32 + kv] = f2bf(v);
    }
  }
  __syncthreads();

  u16* const pw = Ps[wid];
  const float bwv = batch_weight[b];

  for (int mt = 0; mt < 4; ++mt) {
    const int qrow = wid * 64 + mt * 16 + fr;
    bf16x8 qf0 = *(const bf16x8*)(Qbase + qrow * 64 + fkg * 8);
    bf16x8 qf1 = *(const bf16x8*)(Qbase + qrow * 64 + 32 + fkg * 8);

    float mrun[4], lrun[4];
#pragma unroll
    for (int j = 0; j < 4; ++j) { mrun[j] = -1e30f; lrun[j] = 0.f; }
    f32x4 oacc[4] = {};

    for (int c = 0; c < 8; ++c) {
      f32x4 sa[4] = {};
#pragma unroll
      for (int nt = 0; nt < 4; ++nt) {
        int krow = c * 64 + nt * 16 + fr;
        int base = krow * 64;
        bf16x8 kf0 = *(const bf16x8*)(Ks + ((base + fkg * 8) ^ ((krow & 7) << 3)));
        bf16x8 kf1 = *(const bf16x8*)(Ks + ((base + 32 + fkg * 8) ^ ((krow & 7) << 3)));
        sa[nt] = mfma16(qf0, kf0, sa[nt]);
        sa[nt] = mfma16(qf1, kf1, sa[nt]);
      }
#pragma unroll
      for (int nt = 0; nt < 4; ++nt) sa[nt] *= scale;

#pragma unroll
      for (int j = 0; j < 4; ++j) {
        float mx = fmaxf(fmaxf(sa[0][j], sa[1][j]), fmaxf(sa[2][j], sa[3][j]));
#pragma unroll
        for (int msk = 1; msk < 16; msk <<= 1) mx = fmaxf(mx, __shfl_xor(mx, msk, 64));
        float mnew;
        if (__all(mx <= mrun[j] + 8.0f)) {
          mnew = mrun[j];
        } else {
          mnew = fmaxf(mx, mrun[j]);
          float alpha = __expf(mrun[j] - mnew);
          lrun[j] *= alpha;
#pragma unroll
          for (int t = 0; t < 4; ++t) oacc[t][j] *= alpha;
          mrun[j] = mnew;
        }
        float sum = 0.f;
#pragma unroll
        for (int nt = 0; nt < 4; ++nt) {
          float p = __expf(sa[nt][j] - mnew);
          sa[nt][j] = p;
          sum += p;
        }
#pragma unroll
        for (int msk = 1; msk < 16; msk <<= 1) sum += __shfl_xor(sum, msk, 64);
        lrun[j] += sum;
      }

#pragma unroll
      for (int nt = 0; nt < 4; ++nt)
#pragma unroll
        for (int j = 0; j < 4; ++j) {
          int r = fkg * 4 + j;
          pw[(r * 64 + nt * 16 + fr) ^ ((r & 7) << 3)] = f2bf(sa[nt][j]);
        }
#pragma unroll
      for (int kk = 0; kk < 2; ++kk) {
        bf16x8 pa = *(const bf16x8*)(pw + ((fr * 64 + kk * 32 + fkg * 8) ^ ((fr & 7) << 3)));
#pragma unroll
        for (int t = 0; t < 4; ++t) {
          int vd = t * 16 + fr;
          bf16x8 vf = *(const bf16x8*)(VTs + ((vd * 512 + c * 64 + kk * 32 + fkg * 8) ^ ((vd & 7) << 3)));
          oacc[t] = mfma16(pa, vf, oacc[t]);
        }
      }
    }

    f32x4 sp = {};
    {
      bf16x8 pk0 = *(const bf16x8*)(pKs + ((fr * 64 + fkg * 8) ^ ((fr & 7) << 3)));
      bf16x8 pk1 = *(const bf16x8*)(pKs + ((fr * 64 + 32 + fkg * 8) ^ ((fr & 7) << 3)));
      sp = mfma16(qf0, pk0, sp);
      sp = mfma16(qf1, pk1, sp);
    }
    sp *= scale;
    float lp[4];
#pragma unroll
    for (int j = 0; j < 4; ++j) {
      float mx = sp[j];
#pragma unroll
      for (int msk = 1; msk < 16; msk <<= 1) mx = fmaxf(mx, __shfl_xor(mx, msk, 64));
      float p = __expf(sp[j] - mx);
      sp[j] = p;
      float sum = p;
#pragma unroll
      for (int msk = 1; msk < 16; msk <<= 1) sum += __shfl_xor(sum, msk, 64);
      lp[j] = sum;
    }
#pragma unroll
    for (int j = 0; j < 4; ++j) {
      int r = fkg * 4 + j;
      pw[(r * 64 + fr) ^ ((r & 7) << 3)] = f2bf(sp[j]);
      pw[(r * 64 + 16 + fr) ^ ((r & 7) << 3)] = 0;
    }
    f32x4 opacc[4] = {};
    {
      bf16x8 pa = *(const bf16x8*)(pw + ((fr * 64 + fkg * 8) ^ ((fr & 7) << 3)));
#pragma unroll
      for (int t = 0; t < 4; ++t) {
        bf16x8 vf = *(const bf16x8*)(pVTs + (t * 16 + fr) * 32 + fkg * 8);
        opacc[t] = mfma16(pa, vf, opacc[t]);
      }
    }

#pragma unroll
    for (int j = 0; j < 4; ++j) {
      int s = wid * 64 + mt * 16 + fkg * 4 + j;
      float invl = 1.f / lrun[j];
      float invlp = 1.f / lp[j];
      size_t m = (size_t)s * 32 + b;
#pragma unroll
      for (int t = 0; t < 4; ++t) {
        float v = oacc[t][j] * invl + bwv * opacc[t][j] * invlp;
        attn_out[m * E + h * 64 + t * 16 + fr] = f2bf(v);
      }
    }
  }
}

extern "C" void kernel_launch(void* const* d_in, const int* in_sizes, int n_in,
                              void* d_out, int out_size, void* d_ws, size_t ws_size,
                              hipStream_t stream) {
  const float* query = (const float*)d_in[0];
  const int* prompt_ids = (const int*)d_in[1];
  const float* batch_weight = (const float*)d_in[2];
  const float* in_proj_w = (const float*)d_in[3];
  const float* in_proj_b = (const float*)d_in[4];
  const float* out_proj_w = (const float*)d_in[5];
  const float* out_proj_b = (const float*)d_in[6];
  const float* prefix_pool = (const float*)d_in[7];
  float* out = (float*)d_out;

  u16* qbf = (u16*)d_ws;                      // 16384x1024
  u16* wqkv = qbf + (size_t)16384 * 1024;     // 3072x1024
  u16* wout = wqkv + (size_t)3072 * 1024;     // 1024x1024
  u16* qx = wout + (size_t)1024 * 1024;       // [b,h,s,d]
  u16* kx = qx + (size_t)32 * 16 * 512 * 64;
  u16* vx = kx + (size_t)32 * 16 * 512 * 64;
  u16* attnb = vx + (size_t)32 * 16 * 512 * 64;  // 16384x1024

  cvt_f32_bf16<<<16384, 256, 0, stream>>>(query, qbf, 16384 * 1024 / 4);
  cvt_f32_bf16<<<3072, 256, 0, stream>>>(in_proj_w, wqkv, 3072 * 1024 / 4);
  cvt_f32_bf16<<<1024, 256, 0, stream>>>(out_proj_w, wout, 1024 * 1024 / 4);

  gemm8p<2><<<dim3(64, 12), 512, 0, stream>>>(qbf, wqkv, in_proj_b, nullptr,
                                              qx, kx, vx, 16384, 3072, 1024);
  attn_v2<<<dim3(16, 32), 512, 0, stream>>>(qx, kx, vx, prefix_pool, prompt_ids,
                                            batch_weight, attnb);
  gemm8p<0><<<dim3(64, 4), 512, 0, stream>>>(attnb, wout, out_proj_b, out,
                                             nullptr, nullptr, nullptr,
                                             16384, 1024, 1024);
}